// Round 5
// baseline (626.684 us; speedup 1.0000x reference)
//
#include <hip/hip_runtime.h>
#include <hip/hip_bf16.h>
#include <cstdint>

// Problem constants (from reference): B,T,E,C,I_E,O = 4,2048,8,512,512,4096
constexpr int NB = 4;
constexpr int NT = 2048;
constexpr int NE = 8;
constexpr int NC = 512;
constexpr int NI = 512;
constexpr int NO = 4096;
constexpr int NEC = NE * NC;  // 4096 (stage-2 K)

typedef __attribute__((ext_vector_type(8))) short short8;
typedef __attribute__((ext_vector_type(8))) unsigned short ushort8;
typedef __attribute__((ext_vector_type(4))) float f32x4;

// f32 -> bf16 round-to-nearest-even
__device__ __forceinline__ unsigned short f2bf(float f) {
  unsigned int u = __builtin_bit_cast(unsigned int, f);
  u += 0x7FFFu + ((u >> 16) & 1u);
  return (unsigned short)(u >> 16);
}

__device__ __forceinline__ ushort8 cvt8(float4 a, float4 b) {
  ushort8 v;
  v[0] = f2bf(a.x); v[1] = f2bf(a.y); v[2] = f2bf(a.z); v[3] = f2bf(a.w);
  v[4] = f2bf(b.x); v[5] = f2bf(b.y); v[6] = f2bf(b.z); v[7] = f2bf(b.w);
  return v;
}

// async global(16B) -> LDS, wave-uniform LDS base + lane*16 (HW semantics)
__device__ __forceinline__ void gload_lds16(const void* g, void* lds) {
  __builtin_amdgcn_global_load_lds(
      (const __attribute__((address_space(1))) unsigned int*)g,
      (__attribute__((address_space(3))) unsigned int*)lds, 16, 0, 0);
}

// ===========================================================================
// FAST PATH: bf16 operands + global_load_lds (m97 structure)
// ===========================================================================

// f32 -> bf16 conversion, 8 elems/thread/iter, grid-stride
__global__ __launch_bounds__(256) void k_cvt(
    const float* __restrict__ src, unsigned short* __restrict__ dst, int n8) {
  int i = blockIdx.x * blockDim.x + threadIdx.x;
  const int stride = gridDim.x * blockDim.x;
  for (; i < n8; i += stride) {
    const float4* s = (const float4*)(src + (size_t)i * 8);
    float4 a = s[0], b = s[1];
    *(ushort8*)(dst + (size_t)i * 8) = cvt8(a, b);
  }
}

// Shared m97-style core: 128x128 tile, BK=32, 4 waves (2x2), per-wave 64x64.
// LDS linear [128][32] bf16 (8KB each op). Per K-step: 4 gload_lds(16B)/thread,
// 8 ds_read_b128 + 16 MFMA /wave. 8-way read conflict accepted (T2-gate: null
// at 2-phase schedules).
template <int KTOT>
__device__ __forceinline__ void gemm_core(
    const unsigned short* __restrict__ Ag, const unsigned short* __restrict__ Bg,
    int ldk, unsigned short* As, unsigned short* Bs, f32x4 (&acc)[4][4]) {
  const int tid = threadIdx.x, lane = tid & 63, wv = tid >> 6;
  const int wr = wv >> 1, wc = wv & 1;
  const int l4 = lane >> 2, lc = lane & 3;

  for (int k0 = 0; k0 < KTOT; k0 += 32) {
    __syncthreads();  // previous iter's ds_reads complete before overwrite
#pragma unroll
    for (int c = 0; c < 2; ++c) {
      const int q = wv * 2 + c;          // chunk: rows q*16..q*16+15
      const int row = q * 16 + l4;
      const size_t goff = (size_t)row * ldk + k0 + lc * 8;
      gload_lds16(Ag + goff, As + q * 512);  // LDS base wave-uniform
      gload_lds16(Bg + goff, Bs + q * 512);
    }
    __syncthreads();  // compiler drains vmcnt(0) before barrier -> data landed

    const int kb = (lane >> 4) * 16;  // byte offset of this lane's 8 K-elems
    short8 af[4], bfv[4];
#pragma unroll
    for (int m = 0; m < 4; ++m) {
      const int r = wr * 64 + m * 16 + (lane & 15);
      af[m] = *(const short8*)((const char*)As + r * 64 + kb);
    }
#pragma unroll
    for (int n = 0; n < 4; ++n) {
      const int r = wc * 64 + n * 16 + (lane & 15);
      bfv[n] = *(const short8*)((const char*)Bs + r * 64 + kb);
    }
#pragma unroll
    for (int m = 0; m < 4; ++m)
#pragma unroll
      for (int n = 0; n < 4; ++n)
        acc[m][n] = __builtin_amdgcn_mfma_f32_16x16x32_bf16(
            af[m], bfv[n], acc[m][n], 0, 0, 0);
  }
}

// Stage 1 (bf16 in): eoT[b][o][e][c] = sum_i W[e,o,i]*x[b,e,c,i] + bias[o]
__global__ __launch_bounds__(256) void k_gemm1f(
    const unsigned short* __restrict__ xb, const unsigned short* __restrict__ Wb,
    const float* __restrict__ bias, unsigned short* __restrict__ eoT) {
  const int tile = blockIdx.x;  // 32 o-tiles x 4 c-tiles
  const int e = blockIdx.y, b = blockIdx.z;
  const int bm = tile >> 2, bn = tile & 3;
  const int tid = threadIdx.x, lane = tid & 63, wv = tid >> 6;
  const int wr = wv >> 1, wc = wv & 1;

  const unsigned short* Ag = Wb + (size_t)e * NO * NI + (size_t)(bm * 128) * NI;
  const unsigned short* Bg = xb + ((size_t)b * NE + e) * NC * NI + (size_t)(bn * 128) * NI;

  __shared__ __align__(16) unsigned short As[128 * 32];
  __shared__ __align__(16) unsigned short Bs[128 * 32];

  f32x4 acc[4][4];
#pragma unroll
  for (int m = 0; m < 4; ++m)
#pragma unroll
    for (int n = 0; n < 4; ++n) acc[m][n] = (f32x4)0.f;

  gemm_core<NI>(Ag, Bg, NI, As, Bs, acc);

  const int o0 = bm * 128 + wr * 64;
  const int c0 = bn * 128 + wc * 64;
#pragma unroll
  for (int m = 0; m < 4; ++m) {
#pragma unroll
    for (int j = 0; j < 4; ++j) {
      const int o = o0 + m * 16 + (lane >> 4) * 4 + j;
      const float bv = bias[o];
      const size_t base = (((size_t)b * NO + o) * NE + e) * NC + c0;
#pragma unroll
      for (int n = 0; n < 4; ++n)
        eoT[base + n * 16 + (lane & 15)] = f2bf(acc[m][n][j] + bv);
    }
  }
}

// Stage 2 (bf16 in): out[b,t,o] = sum_{ec} comb[b,t,e,c] * eoT[b,o,e,c]
__global__ __launch_bounds__(256) void k_gemm2f(
    const unsigned short* __restrict__ cb, const unsigned short* __restrict__ eoT,
    float* __restrict__ out) {
  const int b = blockIdx.y;
  const int bm = blockIdx.x >> 5;  // t-tile
  const int bn = blockIdx.x & 31;  // o-tile (fast -> A-panel L2 reuse)
  const int tid = threadIdx.x, lane = tid & 63, wv = tid >> 6;
  const int wr = wv >> 1, wc = wv & 1;

  const unsigned short* Ag = cb + (size_t)b * NT * NEC + (size_t)(bm * 128) * NEC;
  const unsigned short* Bg = eoT + (size_t)b * NO * NEC + (size_t)(bn * 128) * NEC;

  __shared__ __align__(16) unsigned short As[128 * 32];
  __shared__ __align__(16) unsigned short Bs[128 * 32];

  f32x4 acc[4][4];
#pragma unroll
  for (int m = 0; m < 4; ++m)
#pragma unroll
    for (int n = 0; n < 4; ++n) acc[m][n] = (f32x4)0.f;

  gemm_core<NEC>(Ag, Bg, NEC, As, Bs, acc);

  const int t0 = bm * 128 + wr * 64;
  const int o0 = bn * 128 + wc * 64;
#pragma unroll
  for (int m = 0; m < 4; ++m) {
#pragma unroll
    for (int j = 0; j < 4; ++j) {
      const int t = t0 + m * 16 + (lane >> 4) * 4 + j;
      float* op = out + ((size_t)b * NT + t) * NO + o0;
#pragma unroll
      for (int n = 0; n < 4; ++n) op[n * 16 + (lane & 15)] = acc[m][n][j];
    }
  }
}

// ===========================================================================
// FALLBACK PATH (round-4 verified kernels) — used when ws_size < 201 MB
// ===========================================================================

__device__ __forceinline__ int lds_byte(int row, int kbyte) {
  return (row * 64 + kbyte) ^ ((row & 6) << 3);
}

__global__ __launch_bounds__(256, 2) void k_gemm1(
    const float* __restrict__ x, const float* __restrict__ W,
    const float* __restrict__ bias, unsigned short* __restrict__ eoT) {
  const int tile = blockIdx.x;
  const int e = blockIdx.y, b = blockIdx.z;
  const int bm = tile >> 2, bn = tile & 3;
  const int tid = threadIdx.x, lane = tid & 63, wv = tid >> 6;
  const int wr = wv >> 1, wc = wv & 1;

  const float* Ag = W + (size_t)e * NO * NI + (size_t)(bm * 128) * NI;
  const float* Bg = x + ((size_t)b * NE + e) * NC * NI + (size_t)(bn * 128) * NI;

  __shared__ __align__(16) unsigned short As[128 * 32];
  __shared__ __align__(16) unsigned short Bs[128 * 32];

  f32x4 acc[4][4];
#pragma unroll
  for (int m = 0; m < 4; ++m)
#pragma unroll
    for (int n = 0; n < 4; ++n) acc[m][n] = (f32x4)0.f;

  for (int k0 = 0; k0 < NI; k0 += 32) {
    __syncthreads();
#pragma unroll
    for (int s = 0; s < 2; ++s) {
      const int q = tid + s * 256;
      const int row = q >> 2, kc = (q & 3) * 8;
      const float* ga = Ag + (size_t)row * NI + k0 + kc;
      float4 a0 = *(const float4*)ga;
      float4 a1 = *(const float4*)(ga + 4);
      *(ushort8*)((char*)As + lds_byte(row, kc * 2)) = cvt8(a0, a1);
      const float* gb = Bg + (size_t)row * NI + k0 + kc;
      float4 b0 = *(const float4*)gb;
      float4 b1 = *(const float4*)(gb + 4);
      *(ushort8*)((char*)Bs + lds_byte(row, kc * 2)) = cvt8(b0, b1);
    }
    __syncthreads();

    const int kb = (lane >> 4) * 16;
    short8 af[4], bfv[4];
#pragma unroll
    for (int m = 0; m < 4; ++m) {
      const int r = wr * 64 + m * 16 + (lane & 15);
      af[m] = *(const short8*)((const char*)As + lds_byte(r, kb));
    }
#pragma unroll
    for (int n = 0; n < 4; ++n) {
      const int r = wc * 64 + n * 16 + (lane & 15);
      bfv[n] = *(const short8*)((const char*)Bs + lds_byte(r, kb));
    }
#pragma unroll
    for (int m = 0; m < 4; ++m)
#pragma unroll
      for (int n = 0; n < 4; ++n)
        acc[m][n] = __builtin_amdgcn_mfma_f32_16x16x32_bf16(
            af[m], bfv[n], acc[m][n], 0, 0, 0);
  }

  const int o0 = bm * 128 + wr * 64;
  const int c0 = bn * 128 + wc * 64;
#pragma unroll
  for (int m = 0; m < 4; ++m) {
#pragma unroll
    for (int j = 0; j < 4; ++j) {
      const int o = o0 + m * 16 + (lane >> 4) * 4 + j;
      const float bv = bias[o];
      const size_t base = (((size_t)b * NO + o) * NE + e) * NC + c0;
#pragma unroll
      for (int n = 0; n < 4; ++n)
        eoT[base + n * 16 + (lane & 15)] = f2bf(acc[m][n][j] + bv);
    }
  }
}

__global__ __launch_bounds__(256, 2) void k_gemm2(
    const float* __restrict__ comb, const unsigned short* __restrict__ eoT,
    float* __restrict__ out) {
  const int b = blockIdx.y;
  const int bm = blockIdx.x >> 5;
  const int bn = blockIdx.x & 31;
  const int tid = threadIdx.x, lane = tid & 63, wv = tid >> 6;
  const int wr = wv >> 1, wc = wv & 1;

  const float* Ag = comb + (size_t)b * NT * NEC + (size_t)(bm * 128) * NEC;
  const unsigned short* Bg = eoT + (size_t)b * NO * NEC + (size_t)(bn * 128) * NEC;

  __shared__ __align__(16) unsigned short As[128 * 32];
  __shared__ __align__(16) unsigned short Bs[128 * 32];

  f32x4 acc[4][4];
#pragma unroll
  for (int m = 0; m < 4; ++m)
#pragma unroll
    for (int n = 0; n < 4; ++n) acc[m][n] = (f32x4)0.f;

  for (int k0 = 0; k0 < NEC; k0 += 32) {
    __syncthreads();
#pragma unroll
    for (int s = 0; s < 2; ++s) {
      const int q = tid + s * 256;
      const int row = q >> 2, kc = (q & 3) * 8;
      const float* ga = Ag + (size_t)row * NEC + k0 + kc;
      float4 a0 = *(const float4*)ga;
      float4 a1 = *(const float4*)(ga + 4);
      *(ushort8*)((char*)As + lds_byte(row, kc * 2)) = cvt8(a0, a1);
      ushort8 bv = *(const ushort8*)(Bg + (size_t)row * NEC + k0 + kc);
      *(ushort8*)((char*)Bs + lds_byte(row, kc * 2)) = bv;
    }
    __syncthreads();

    const int kb = (lane >> 4) * 16;
    short8 af[4], bfv[4];
#pragma unroll
    for (int m = 0; m < 4; ++m) {
      const int r = wr * 64 + m * 16 + (lane & 15);
      af[m] = *(const short8*)((const char*)As + lds_byte(r, kb));
    }
#pragma unroll
    for (int n = 0; n < 4; ++n) {
      const int r = wc * 64 + n * 16 + (lane & 15);
      bfv[n] = *(const short8*)((const char*)Bs + lds_byte(r, kb));
    }
#pragma unroll
    for (int m = 0; m < 4; ++m)
#pragma unroll
      for (int n = 0; n < 4; ++n)
        acc[m][n] = __builtin_amdgcn_mfma_f32_16x16x32_bf16(
            af[m], bfv[n], acc[m][n], 0, 0, 0);
  }

  const int t0 = bm * 128 + wr * 64;
  const int o0 = bn * 128 + wc * 64;
#pragma unroll
  for (int m = 0; m < 4; ++m) {
#pragma unroll
    for (int j = 0; j < 4; ++j) {
      const int t = t0 + m * 16 + (lane >> 4) * 4 + j;
      float* op = out + ((size_t)b * NT + t) * NO + o0;
#pragma unroll
      for (int n = 0; n < 4; ++n) op[n * 16 + (lane & 15)] = acc[m][n][j];
    }
  }
}

extern "C" void kernel_launch(void* const* d_in, const int* in_sizes, int n_in,
                              void* d_out, int out_size, void* d_ws, size_t ws_size,
                              hipStream_t stream) {
  const float* x    = (const float*)d_in[0];  // [B,E,C,I]
  const float* comb = (const float*)d_in[1];  // [B,T,E,C]
  const float* W    = (const float*)d_in[2];  // [E,O,I]
  const float* bias = (const float*)d_in[3];  // [O]
  float* out = (float*)d_out;                 // [B,T,O]

  const size_t EOT_ELEMS = (size_t)NB * NO * NE * NC;   // 67,108,864 (x2B = 134MB)
  const size_t X_ELEMS   = (size_t)NB * NE * NC * NI;   //  8,388,608
  const size_t W_ELEMS   = (size_t)NE * NO * NI;        // 16,777,216
  const size_t C_ELEMS   = (size_t)NB * NT * NE * NC;   // 33,554,432
  const size_t region2_elems = (C_ELEMS > X_ELEMS + W_ELEMS) ? C_ELEMS : (X_ELEMS + W_ELEMS);
  const size_t need = (EOT_ELEMS + region2_elems) * 2;  // bytes = 201,326,592

  unsigned short* eoT = (unsigned short*)d_ws;

  if (ws_size >= need) {
    // Fast path: convert to bf16, GEMMs via global_load_lds (m97 structure).
    // region2 time-shared: {xb, Wb} for stage 1, then comb_bf16 for stage 2
    // (stream-ordered, so the overwrite is safe).
    unsigned short* reg2 = eoT + EOT_ELEMS;
    unsigned short* xb = reg2;
    unsigned short* Wb = reg2 + X_ELEMS;
    unsigned short* cb = reg2;

    k_cvt<<<2048, 256, 0, stream>>>(x, xb, (int)(X_ELEMS / 8));
    k_cvt<<<2048, 256, 0, stream>>>(W, Wb, (int)(W_ELEMS / 8));
    k_gemm1f<<<dim3(128, NE, NB), 256, 0, stream>>>(xb, Wb, bias, eoT);
    k_cvt<<<2048, 256, 0, stream>>>(comb, cb, (int)(C_ELEMS / 8));
    k_gemm2f<<<dim3(512, NB), 256, 0, stream>>>(cb, eoT, out);
  } else {
    // Fallback: round-4 verified reg-staged kernels (needs only eoT = 134MB)
    k_gemm1<<<dim3(128, NE, NB), 256, 0, stream>>>(x, W, bias, eoT);
    k_gemm2<<<dim3(512, NB), 256, 0, stream>>>(comb, eoT, out);
  }
}

// Round 6
// 515.611 us; speedup vs baseline: 1.2154x; 1.2154x over previous
//
#include <hip/hip_runtime.h>
#include <hip/hip_bf16.h>
#include <cstdint>

// Problem constants (from reference): B,T,E,C,I_E,O = 4,2048,8,512,512,4096
constexpr int NB = 4;
constexpr int NT = 2048;
constexpr int NE = 8;
constexpr int NC = 512;
constexpr int NI = 512;
constexpr int NO = 4096;
constexpr int NEC = NE * NC;  // 4096 (stage-2 K)

typedef __attribute__((ext_vector_type(8))) short short8;
typedef __attribute__((ext_vector_type(8))) unsigned short ushort8;
typedef __attribute__((ext_vector_type(4))) float f32x4;

// f32 -> bf16 round-to-nearest-even
__device__ __forceinline__ unsigned short f2bf(float f) {
  unsigned int u = __builtin_bit_cast(unsigned int, f);
  u += 0x7FFFu + ((u >> 16) & 1u);
  return (unsigned short)(u >> 16);
}

__device__ __forceinline__ ushort8 cvt8(float4 a, float4 b) {
  ushort8 v;
  v[0] = f2bf(a.x); v[1] = f2bf(a.y); v[2] = f2bf(a.z); v[3] = f2bf(a.w);
  v[4] = f2bf(b.x); v[5] = f2bf(b.y); v[6] = f2bf(b.z); v[7] = f2bf(b.w);
  return v;
}

// XOR-swizzle: byte offset within a [row][64B] tile. Involution on bits 4-5.
// Read side: fragment lanes 0..15 hit rows r..r+15 at fixed kb -> 8 distinct
// 16B slots per 8-row stripe -> 2-way (free) bank aliasing.
__device__ __forceinline__ int lds_byte(int row, int kbyte) {
  return (row * 64 + kbyte) ^ ((row & 6) << 3);
}

// async global(16B) -> LDS, wave-uniform LDS base + lane*16 (HW semantics)
__device__ __forceinline__ void gload_lds16(const void* g, void* lds) {
  __builtin_amdgcn_global_load_lds(
      (const __attribute__((address_space(1))) unsigned int*)g,
      (__attribute__((address_space(3))) unsigned int*)lds, 16, 0, 0);
}

// ===========================================================================
// FAST PATH: bf16 operands + global_load_lds with PRE-SWIZZLED SOURCE
// (rule #21: linear LDS dest + inverse-swizzled global src + swizzled read)
// ===========================================================================

// f32 -> bf16 conversion, 8 elems/thread/iter, grid-stride
__global__ __launch_bounds__(256) void k_cvt(
    const float* __restrict__ src, unsigned short* __restrict__ dst, int n8) {
  int i = blockIdx.x * blockDim.x + threadIdx.x;
  const int stride = gridDim.x * blockDim.x;
  for (; i < n8; i += stride) {
    const float4* s = (const float4*)(src + (size_t)i * 8);
    float4 a = s[0], b = s[1];
    *(ushort8*)(dst + (size_t)i * 8) = cvt8(a, b);
  }
}

// m97-style core: 128x128 tile, BK=32, 4 waves (2x2), per-wave 64x64.
// LDS [128][32] bf16 (8KB/op), content stored in SWIZZLED layout via
// source-permuted gload_lds. Per K-step: 4 gload_lds(16B)/thread,
// 8 ds_read_b128 + 16 MFMA /wave, conflict-free reads.
template <int KTOT>
__device__ __forceinline__ void gemm_core(
    const unsigned short* __restrict__ Ag, const unsigned short* __restrict__ Bg,
    int ldk, unsigned short* As, unsigned short* Bs, f32x4 (&acc)[4][4]) {
  const int tid = threadIdx.x, lane = tid & 63, wv = tid >> 6;
  const int wr = wv >> 1, wc = wv & 1;
  const int l4 = lane >> 2, lc = lane & 3;
  // lane's dest byte = q*1024 + l4*64 + lc*16. For the swizzled read to find
  // (row, kb) at lds_byte(row,kb), this lane must FETCH global chunk
  // kb = lc*16 ^ ((l4&6)<<3)  (short units: lc*8 ^ ((l4&6)<<2)).
  const int kfetch = (lc * 8) ^ ((l4 & 6) << 2);

  for (int k0 = 0; k0 < KTOT; k0 += 32) {
    __syncthreads();  // previous iter's ds_reads complete before overwrite
#pragma unroll
    for (int c = 0; c < 2; ++c) {
      const int q = wv * 2 + c;          // chunk: rows q*16..q*16+15
      const int row = q * 16 + l4;
      const size_t goff = (size_t)row * ldk + k0 + kfetch;
      gload_lds16(Ag + goff, As + q * 512);  // LDS base wave-uniform, linear
      gload_lds16(Bg + goff, Bs + q * 512);
    }
    __syncthreads();  // vmcnt(0) drained before barrier -> data landed

    const int kb = (lane >> 4) * 16;  // byte offset of this lane's 8 K-elems
    short8 af[4], bfv[4];
#pragma unroll
    for (int m = 0; m < 4; ++m) {
      const int r = wr * 64 + m * 16 + (lane & 15);
      af[m] = *(const short8*)((const char*)As + lds_byte(r, kb));
    }
#pragma unroll
    for (int n = 0; n < 4; ++n) {
      const int r = wc * 64 + n * 16 + (lane & 15);
      bfv[n] = *(const short8*)((const char*)Bs + lds_byte(r, kb));
    }
#pragma unroll
    for (int m = 0; m < 4; ++m)
#pragma unroll
      for (int n = 0; n < 4; ++n)
        acc[m][n] = __builtin_amdgcn_mfma_f32_16x16x32_bf16(
            af[m], bfv[n], acc[m][n], 0, 0, 0);
  }
}

// Stage 1 (bf16 in): eoT[b][o][e][c] = sum_i W[e,o,i]*x[b,e,c,i] + bias[o]
__global__ __launch_bounds__(256, 2) void k_gemm1f(
    const unsigned short* __restrict__ xb, const unsigned short* __restrict__ Wb,
    const float* __restrict__ bias, unsigned short* __restrict__ eoT) {
  const int tile = blockIdx.x;  // 32 o-tiles x 4 c-tiles
  const int e = blockIdx.y, b = blockIdx.z;
  const int bm = tile >> 2, bn = tile & 3;
  const int tid = threadIdx.x, lane = tid & 63, wv = tid >> 6;
  const int wr = wv >> 1, wc = wv & 1;

  const unsigned short* Ag = Wb + (size_t)e * NO * NI + (size_t)(bm * 128) * NI;
  const unsigned short* Bg = xb + ((size_t)b * NE + e) * NC * NI + (size_t)(bn * 128) * NI;

  __shared__ __align__(16) unsigned short As[128 * 32];
  __shared__ __align__(16) unsigned short Bs[128 * 32];

  f32x4 acc[4][4];
#pragma unroll
  for (int m = 0; m < 4; ++m)
#pragma unroll
    for (int n = 0; n < 4; ++n) acc[m][n] = (f32x4)0.f;

  gemm_core<NI>(Ag, Bg, NI, As, Bs, acc);

  const int o0 = bm * 128 + wr * 64;
  const int c0 = bn * 128 + wc * 64;
#pragma unroll
  for (int m = 0; m < 4; ++m) {
#pragma unroll
    for (int j = 0; j < 4; ++j) {
      const int o = o0 + m * 16 + (lane >> 4) * 4 + j;
      const float bv = bias[o];
      const size_t base = (((size_t)b * NO + o) * NE + e) * NC + c0;
#pragma unroll
      for (int n = 0; n < 4; ++n)
        eoT[base + n * 16 + (lane & 15)] = f2bf(acc[m][n][j] + bv);
    }
  }
}

// Stage 2 (bf16 in): out[b,t,o] = sum_{ec} comb[b,t,e,c] * eoT[b,o,e,c]
__global__ __launch_bounds__(256, 2) void k_gemm2f(
    const unsigned short* __restrict__ cb, const unsigned short* __restrict__ eoT,
    float* __restrict__ out) {
  const int b = blockIdx.y;
  const int bm = blockIdx.x >> 5;  // t-tile
  const int bn = blockIdx.x & 31;  // o-tile (fast -> A-panel L2 reuse)
  const int tid = threadIdx.x, lane = tid & 63, wv = tid >> 6;
  const int wr = wv >> 1, wc = wv & 1;

  const unsigned short* Ag = cb + (size_t)b * NT * NEC + (size_t)(bm * 128) * NEC;
  const unsigned short* Bg = eoT + (size_t)b * NO * NEC + (size_t)(bn * 128) * NEC;

  __shared__ __align__(16) unsigned short As[128 * 32];
  __shared__ __align__(16) unsigned short Bs[128 * 32];

  f32x4 acc[4][4];
#pragma unroll
  for (int m = 0; m < 4; ++m)
#pragma unroll
    for (int n = 0; n < 4; ++n) acc[m][n] = (f32x4)0.f;

  gemm_core<NEC>(Ag, Bg, NEC, As, Bs, acc);

  const int t0 = bm * 128 + wr * 64;
  const int o0 = bn * 128 + wc * 64;
#pragma unroll
  for (int m = 0; m < 4; ++m) {
#pragma unroll
    for (int j = 0; j < 4; ++j) {
      const int t = t0 + m * 16 + (lane >> 4) * 4 + j;
      float* op = out + ((size_t)b * NT + t) * NO + o0;
#pragma unroll
      for (int n = 0; n < 4; ++n) op[n * 16 + (lane & 15)] = acc[m][n][j];
    }
  }
}

// ===========================================================================
// FALLBACK PATH (round-4 verified kernels) — used when ws_size < 201 MB
// ===========================================================================

__global__ __launch_bounds__(256, 2) void k_gemm1(
    const float* __restrict__ x, const float* __restrict__ W,
    const float* __restrict__ bias, unsigned short* __restrict__ eoT) {
  const int tile = blockIdx.x;
  const int e = blockIdx.y, b = blockIdx.z;
  const int bm = tile >> 2, bn = tile & 3;
  const int tid = threadIdx.x, lane = tid & 63, wv = tid >> 6;
  const int wr = wv >> 1, wc = wv & 1;

  const float* Ag = W + (size_t)e * NO * NI + (size_t)(bm * 128) * NI;
  const float* Bg = x + ((size_t)b * NE + e) * NC * NI + (size_t)(bn * 128) * NI;

  __shared__ __align__(16) unsigned short As[128 * 32];
  __shared__ __align__(16) unsigned short Bs[128 * 32];

  f32x4 acc[4][4];
#pragma unroll
  for (int m = 0; m < 4; ++m)
#pragma unroll
    for (int n = 0; n < 4; ++n) acc[m][n] = (f32x4)0.f;

  for (int k0 = 0; k0 < NI; k0 += 32) {
    __syncthreads();
#pragma unroll
    for (int s = 0; s < 2; ++s) {
      const int q = tid + s * 256;
      const int row = q >> 2, kc = (q & 3) * 8;
      const float* ga = Ag + (size_t)row * NI + k0 + kc;
      float4 a0 = *(const float4*)ga;
      float4 a1 = *(const float4*)(ga + 4);
      *(ushort8*)((char*)As + lds_byte(row, kc * 2)) = cvt8(a0, a1);
      const float* gb = Bg + (size_t)row * NI + k0 + kc;
      float4 b0 = *(const float4*)gb;
      float4 b1 = *(const float4*)(gb + 4);
      *(ushort8*)((char*)Bs + lds_byte(row, kc * 2)) = cvt8(b0, b1);
    }
    __syncthreads();

    const int kb = (lane >> 4) * 16;
    short8 af[4], bfv[4];
#pragma unroll
    for (int m = 0; m < 4; ++m) {
      const int r = wr * 64 + m * 16 + (lane & 15);
      af[m] = *(const short8*)((const char*)As + lds_byte(r, kb));
    }
#pragma unroll
    for (int n = 0; n < 4; ++n) {
      const int r = wc * 64 + n * 16 + (lane & 15);
      bfv[n] = *(const short8*)((const char*)Bs + lds_byte(r, kb));
    }
#pragma unroll
    for (int m = 0; m < 4; ++m)
#pragma unroll
      for (int n = 0; n < 4; ++n)
        acc[m][n] = __builtin_amdgcn_mfma_f32_16x16x32_bf16(
            af[m], bfv[n], acc[m][n], 0, 0, 0);
  }

  const int o0 = bm * 128 + wr * 64;
  const int c0 = bn * 128 + wc * 64;
#pragma unroll
  for (int m = 0; m < 4; ++m) {
#pragma unroll
    for (int j = 0; j < 4; ++j) {
      const int o = o0 + m * 16 + (lane >> 4) * 4 + j;
      const float bv = bias[o];
      const size_t base = (((size_t)b * NO + o) * NE + e) * NC + c0;
#pragma unroll
      for (int n = 0; n < 4; ++n)
        eoT[base + n * 16 + (lane & 15)] = f2bf(acc[m][n][j] + bv);
    }
  }
}

__global__ __launch_bounds__(256, 2) void k_gemm2(
    const float* __restrict__ comb, const unsigned short* __restrict__ eoT,
    float* __restrict__ out) {
  const int b = blockIdx.y;
  const int bm = blockIdx.x >> 5;
  const int bn = blockIdx.x & 31;
  const int tid = threadIdx.x, lane = tid & 63, wv = tid >> 6;
  const int wr = wv >> 1, wc = wv & 1;

  const float* Ag = comb + (size_t)b * NT * NEC + (size_t)(bm * 128) * NEC;
  const unsigned short* Bg = eoT + (size_t)b * NO * NEC + (size_t)(bn * 128) * NEC;

  __shared__ __align__(16) unsigned short As[128 * 32];
  __shared__ __align__(16) unsigned short Bs[128 * 32];

  f32x4 acc[4][4];
#pragma unroll
  for (int m = 0; m < 4; ++m)
#pragma unroll
    for (int n = 0; n < 4; ++n) acc[m][n] = (f32x4)0.f;

  for (int k0 = 0; k0 < NEC; k0 += 32) {
    __syncthreads();
#pragma unroll
    for (int s = 0; s < 2; ++s) {
      const int q = tid + s * 256;
      const int row = q >> 2, kc = (q & 3) * 8;
      const float* ga = Ag + (size_t)row * NEC + k0 + kc;
      float4 a0 = *(const float4*)ga;
      float4 a1 = *(const float4*)(ga + 4);
      *(ushort8*)((char*)As + lds_byte(row, kc * 2)) = cvt8(a0, a1);
      ushort8 bv = *(const ushort8*)(Bg + (size_t)row * NEC + k0 + kc);
      *(ushort8*)((char*)Bs + lds_byte(row, kc * 2)) = bv;
    }
    __syncthreads();

    const int kb = (lane >> 4) * 16;
    short8 af[4], bfv[4];
#pragma unroll
    for (int m = 0; m < 4; ++m) {
      const int r = wr * 64 + m * 16 + (lane & 15);
      af[m] = *(const short8*)((const char*)As + lds_byte(r, kb));
    }
#pragma unroll
    for (int n = 0; n < 4; ++n) {
      const int r = wc * 64 + n * 16 + (lane & 15);
      bfv[n] = *(const short8*)((const char*)Bs + lds_byte(r, kb));
    }
#pragma unroll
    for (int m = 0; m < 4; ++m)
#pragma unroll
      for (int n = 0; n < 4; ++n)
        acc[m][n] = __builtin_amdgcn_mfma_f32_16x16x32_bf16(
            af[m], bfv[n], acc[m][n], 0, 0, 0);
  }

  const int t0 = bm * 128 + wr * 64;
  const int o0 = bn * 128 + wc * 64;
#pragma unroll
  for (int m = 0; m < 4; ++m) {
#pragma unroll
    for (int j = 0; j < 4; ++j) {
      const int t = t0 + m * 16 + (lane >> 4) * 4 + j;
      float* op = out + ((size_t)b * NT + t) * NO + o0;
#pragma unroll
      for (int n = 0; n < 4; ++n) op[n * 16 + (lane & 15)] = acc[m][n][j];
    }
  }
}

extern "C" void kernel_launch(void* const* d_in, const int* in_sizes, int n_in,
                              void* d_out, int out_size, void* d_ws, size_t ws_size,
                              hipStream_t stream) {
  const float* x    = (const float*)d_in[0];  // [B,E,C,I]
  const float* comb = (const float*)d_in[1];  // [B,T,E,C]
  const float* W    = (const float*)d_in[2];  // [E,O,I]
  const float* bias = (const float*)d_in[3];  // [O]
  float* out = (float*)d_out;                 // [B,T,O]

  const size_t EOT_ELEMS = (size_t)NB * NO * NE * NC;   // 67,108,864 (x2B = 134MB)
  const size_t X_ELEMS   = (size_t)NB * NE * NC * NI;   //  8,388,608
  const size_t W_ELEMS   = (size_t)NE * NO * NI;        // 16,777,216
  const size_t C_ELEMS   = (size_t)NB * NT * NE * NC;   // 33,554,432
  const size_t region2_elems = (C_ELEMS > X_ELEMS + W_ELEMS) ? C_ELEMS : (X_ELEMS + W_ELEMS);
  const size_t need = (EOT_ELEMS + region2_elems) * 2;  // bytes = 201,326,592

  unsigned short* eoT = (unsigned short*)d_ws;

  if (ws_size >= need) {
    // Fast path: convert to bf16, GEMMs via source-swizzled global_load_lds.
    // region2 time-shared: {xb, Wb} for stage 1, then comb_bf16 for stage 2.
    unsigned short* reg2 = eoT + EOT_ELEMS;
    unsigned short* xb = reg2;
    unsigned short* Wb = reg2 + X_ELEMS;
    unsigned short* cb = reg2;

    k_cvt<<<2048, 256, 0, stream>>>(x, xb, (int)(X_ELEMS / 8));
    k_cvt<<<2048, 256, 0, stream>>>(W, Wb, (int)(W_ELEMS / 8));
    k_gemm1f<<<dim3(128, NE, NB), 256, 0, stream>>>(xb, Wb, bias, eoT);
    k_cvt<<<2048, 256, 0, stream>>>(comb, cb, (int)(C_ELEMS / 8));
    k_gemm2f<<<dim3(512, NB), 256, 0, stream>>>(cb, eoT, out);
  } else {
    // Fallback: round-4 verified reg-staged kernels (needs only eoT = 134MB)
    k_gemm1<<<dim3(128, NE, NB), 256, 0, stream>>>(x, W, bias, eoT);
    k_gemm2<<<dim3(512, NB), 256, 0, stream>>>(comb, eoT, out);
  }
}